// Round 1
// 5820.339 us; speedup vs baseline: 1.1763x; 1.1763x over previous
//
#include <hip/hip_runtime.h>

#define H 100
#define FIN 2
#define KORD 5

typedef unsigned int uint32;
typedef unsigned short ushort16;
typedef __attribute__((ext_vector_type(8))) short s8v;   // 8 x bf16 (4 VGPRs)
typedef __attribute__((ext_vector_type(4))) float f4v;   // MFMA accumulator

__device__ __forceinline__ ushort16 f2b(float x) {  // fp32 -> bf16 RNE
  uint32 u = __float_as_uint(x);
  return (ushort16)((u + 0x7fffu + ((u >> 16) & 1u)) >> 16);
}
__device__ __forceinline__ float2 b2f2(uint32 v) {  // packed bf16x2 -> 2 fp32
  return make_float2(__uint_as_float(v << 16), __uint_as_float(v & 0xffff0000u));
}

// ---------------- graph setup ----------------

__global__ __launch_bounds__(256) void deg_kernel(const int* __restrict__ src, const int* __restrict__ dst,
                                                  float* __restrict__ deg, int* __restrict__ indeg, int E) {
  int e = blockIdx.x * 256 + threadIdx.x;
  if (e < E) {
    atomicAdd(&deg[src[e]], 1.0f);
    atomicAdd(&indeg[dst[e]], 1);
  }
}

__global__ __launch_bounds__(256) void dinv_kernel(const float* __restrict__ deg, float* __restrict__ dinv, int n) {
  int i = blockIdx.x * 256 + threadIdx.x;
  if (i < n) {
    float d = deg[i];
    dinv[i] = d > 0.f ? rsqrtf(fmaxf(d, 1.f)) : 0.f;
  }
}

__global__ __launch_bounds__(256) void scan_block(const int* __restrict__ in, int* __restrict__ incl,
                                                  int* __restrict__ bsum, int n) {
  __shared__ int s[256];
  int i = blockIdx.x * 256 + threadIdx.x;
  int v = (i < n) ? in[i] : 0;
  s[threadIdx.x] = v;
  __syncthreads();
  for (int d = 1; d < 256; d <<= 1) {
    int t = (threadIdx.x >= d) ? s[threadIdx.x - d] : 0;
    __syncthreads();
    s[threadIdx.x] += t;
    __syncthreads();
  }
  if (i < n) incl[i] = s[threadIdx.x];
  if (threadIdx.x == 255) bsum[blockIdx.x] = s[255];
}

__global__ __launch_bounds__(256) void scan_sums(const int* __restrict__ bsum, int* __restrict__ bscan, int nb) {
  __shared__ int s[256];
  __shared__ int carry;
  if (threadIdx.x == 0) carry = 0;
  __syncthreads();
  for (int base = 0; base < nb; base += 256) {
    int i = base + threadIdx.x;
    int v = (i < nb) ? bsum[i] : 0;
    s[threadIdx.x] = v;
    __syncthreads();
    for (int d = 1; d < 256; d <<= 1) {
      int t = (threadIdx.x >= d) ? s[threadIdx.x - d] : 0;
      __syncthreads();
      s[threadIdx.x] += t;
      __syncthreads();
    }
    int c = carry;
    if (i < nb) bscan[i] = s[threadIdx.x] + c;
    __syncthreads();
    if (threadIdx.x == 0) carry = c + s[255];
    __syncthreads();
  }
}

__global__ __launch_bounds__(256) void finalize_offsets(const int* __restrict__ incl, const int* __restrict__ indeg,
                                                        const int* __restrict__ bscan, int* __restrict__ offsets,
                                                        int* __restrict__ cursor, int n, int total) {
  int i = blockIdx.x * 256 + threadIdx.x;
  if (i < n) {
    int prev = (blockIdx.x > 0) ? bscan[blockIdx.x - 1] : 0;
    int excl = incl[i] - indeg[i] + prev;
    offsets[i] = excl;
    cursor[i] = excl;
  }
  if (i == 0) offsets[n] = total;
}

// CSR entry packed (src, norm-bits): one 8B scattered store instead of two 4B stores.
__global__ __launch_bounds__(256) void build_csr(const int* __restrict__ src, const int* __restrict__ dst,
                                                 const float* __restrict__ dinv, int* __restrict__ cursor,
                                                 int2* __restrict__ csr, int E) {
  int e = blockIdx.x * 256 + threadIdx.x;
  if (e < E) {
    int s = src[e], d = dst[e];
    float nrm = -dinv[s] * dinv[d];
    int p = atomicAdd(&cursor[d], 1);
    csr[p] = make_int2(s, __float_as_int(nrm));
  }
}

// Zero the pad quads (uint32 48..63 = bf16 features 96..127) of row-stride-128 bf16 buffer.
// Real features 96..99 are rewritten element-wise by bn_final_bf16 afterwards; features
// 100..127 must be zero because gemm_mfma's A-fragments read K=100..127 (x0 B-weights; NaN*0=NaN).
__global__ __launch_bounds__(256) void pad_zero(uint4* __restrict__ b, int nrows) {
  int i = blockIdx.x * 256 + threadIdx.x;
  if (i < nrows * 4) {
    uint4 z; z.x = 0; z.y = 0; z.z = 0; z.w = 0;
    b[(size_t)(i >> 2) * 16 + 12 + (i & 3)] = z;
  }
}

// ---------------- propagate ----------------

// F=2 props for layer 0 (thread per node), 4x unrolled
__global__ __launch_bounds__(256) void prop2(const float* __restrict__ h, const float* __restrict__ prev,
                                             float* __restrict__ out, const int* __restrict__ offs,
                                             const int2* __restrict__ csr, int n, int mode) {
  int i = blockIdx.x * 256 + threadIdx.x;
  if (i >= n) return;
  float a0 = 0.f, a1 = 0.f;
  int e0 = offs[i], e1 = offs[i + 1];
  int e = e0;
  for (; e + 4 <= e1; e += 4) {
    int2 c0 = csr[e], c1 = csr[e + 1], c2 = csr[e + 2], c3 = csr[e + 3];
    float w0 = __int_as_float(c0.y), w1 = __int_as_float(c1.y);
    float w2 = __int_as_float(c2.y), w3 = __int_as_float(c3.y);
    float x0 = h[2 * c0.x], y0 = h[2 * c0.x + 1];
    float x1 = h[2 * c1.x], y1 = h[2 * c1.x + 1];
    float x2 = h[2 * c2.x], y2 = h[2 * c2.x + 1];
    float x3 = h[2 * c3.x], y3 = h[2 * c3.x + 1];
    a0 = fmaf(w0, x0, a0); a1 = fmaf(w0, y0, a1);
    a0 = fmaf(w1, x1, a0); a1 = fmaf(w1, y1, a1);
    a0 = fmaf(w2, x2, a0); a1 = fmaf(w2, y2, a1);
    a0 = fmaf(w3, x3, a0); a1 = fmaf(w3, y3, a1);
  }
  for (; e < e1; ++e) {
    int2 c = csr[e];
    float w = __int_as_float(c.y);
    a0 = fmaf(w, h[2 * c.x], a0);
    a1 = fmaf(w, h[2 * c.x + 1], a1);
  }
  if (mode) {
    a0 = 2.f * a0 - prev[2 * i];
    a1 = 2.f * a1 - prev[2 * i + 1];
  }
  out[2 * i] = a0;
  out[2 * i + 1] = a1;
}

// bf16 prop, wave per node, 4 nodes/block.
// New structure: 4 edges processed simultaneously by four 16-lane groups; each lane gathers
// dwordx4 (16B = 8 features). Up to 64 edges' (src,norm) loaded cooperatively once (one int2
// per lane) and distributed by shfl -- no serial csr-load -> gather dependency. Each round
// issues 2 independent 4-edge gathers (8 edges / ~1.6KB in flight per wave). Cross-group
// reduce via 2x shfl_xor; group 0 writes the full 256B row (pads exact zero).
__global__ __launch_bounds__(256) void prop_hb(const uint32* __restrict__ h, const uint32* __restrict__ prev,
                                               uint32* __restrict__ out, const int* __restrict__ offs,
                                               const int2* __restrict__ csr, int n, int mode) {
  int lane = threadIdx.x & 63;
  int node = blockIdx.x * 4 + (threadIdx.x >> 6);
  if (node >= n) return;
  int grp = lane >> 4, sub = lane & 15;
  int e0 = offs[node], e1 = offs[node + 1];
  const uint4* hq = (const uint4*)h;

  float a[8];
#pragma unroll
  for (int j = 0; j < 8; ++j) a[j] = 0.f;

  for (int base = e0; base < e1; base += 64) {  // outer loop runs once for deg<=64 (always here)
    int mm = e1 - base;
    int2 cv = make_int2(0, 0);                  // inactive slots: src=0 (valid addr), w=+0
    if (lane < mm) cv = csr[base + lane];
    int lim = mm < 64 ? mm : 64;
    int nr = (lim + 7) >> 3;                    // rounds of 8 edges
    for (int r = 0; r < nr; ++r) {
      int ea = 8 * r + grp;
      int sa = __shfl(cv.x, ea);
      float wa = __int_as_float(__shfl(cv.y, ea));
      int sb = __shfl(cv.x, ea + 4);
      float wb = __int_as_float(__shfl(cv.y, ea + 4));
      uint4 va = hq[(size_t)sa * 16 + sub];
      uint4 vb = hq[(size_t)sb * 16 + sub];
      float2 f;
      f = b2f2(va.x); a[0] = fmaf(wa, f.x, a[0]); a[1] = fmaf(wa, f.y, a[1]);
      f = b2f2(va.y); a[2] = fmaf(wa, f.x, a[2]); a[3] = fmaf(wa, f.y, a[3]);
      f = b2f2(va.z); a[4] = fmaf(wa, f.x, a[4]); a[5] = fmaf(wa, f.y, a[5]);
      f = b2f2(va.w); a[6] = fmaf(wa, f.x, a[6]); a[7] = fmaf(wa, f.y, a[7]);
      f = b2f2(vb.x); a[0] = fmaf(wb, f.x, a[0]); a[1] = fmaf(wb, f.y, a[1]);
      f = b2f2(vb.y); a[2] = fmaf(wb, f.x, a[2]); a[3] = fmaf(wb, f.y, a[3]);
      f = b2f2(vb.z); a[4] = fmaf(wb, f.x, a[4]); a[5] = fmaf(wb, f.y, a[5]);
      f = b2f2(vb.w); a[6] = fmaf(wb, f.x, a[6]); a[7] = fmaf(wb, f.y, a[7]);
    }
  }

  // reduce partial sums across the 4 edge-groups (lanes l, l+16, l+32, l+48 share features)
#pragma unroll
  for (int j = 0; j < 8; ++j) a[j] += __shfl_xor(a[j], 16);
#pragma unroll
  for (int j = 0; j < 8; ++j) a[j] += __shfl_xor(a[j], 32);

  if (grp != 0) return;  // group 0 writes the full row: 16 lanes x 16B = 256B coalesced
  uint4* oq = (uint4*)out;
  size_t qi = (size_t)node * 16 + sub;
  if (sub >= 13) {  // pure pad quads (features 104..127): keep exact zero
    uint4 z; z.x = 0; z.y = 0; z.z = 0; z.w = 0;
    oq[qi] = z;
    return;
  }
  if (sub == 12) { a[4] = 0.f; a[5] = 0.f; a[6] = 0.f; a[7] = 0.f; }  // features 100..103 = pad
  float rr[8];
  if (mode) {  // out = 2*prop - prev ; prev pads are zero so pads stay exactly zero
    uint4 pv = ((const uint4*)prev)[qi];
    float2 p;
    p = b2f2(pv.x); rr[0] = 2.f * a[0] - p.x; rr[1] = 2.f * a[1] - p.y;
    p = b2f2(pv.y); rr[2] = 2.f * a[2] - p.x; rr[3] = 2.f * a[3] - p.y;
    p = b2f2(pv.z); rr[4] = 2.f * a[4] - p.x; rr[5] = 2.f * a[5] - p.y;
    p = b2f2(pv.w); rr[6] = 2.f * a[6] - p.x; rr[7] = 2.f * a[7] - p.y;
  } else {
#pragma unroll
    for (int j = 0; j < 8; ++j) rr[j] = a[j];
  }
  uint4 pk;
  pk.x = (uint32)f2b(rr[0]) | ((uint32)f2b(rr[1]) << 16);
  pk.y = (uint32)f2b(rr[2]) | ((uint32)f2b(rr[3]) << 16);
  pk.z = (uint32)f2b(rr[4]) | ((uint32)f2b(rr[5]) << 16);
  pk.w = (uint32)f2b(rr[6]) | ((uint32)f2b(rr[7]) << 16);
  oq[qi] = pk;
}

// ---------------- W repack: fp32 [mat][c][f] -> bf16 MFMA B-fragments ----------------

__global__ __launch_bounds__(64) void wconv(const float* __restrict__ Wr, ushort16* __restrict__ Wf) {
  int b = blockIdx.x;
  int l = threadIdx.x;
  int mat = b / 28, rem = b % 28;
  int kc = rem / 7, ft = rem % 7;
  const float* Wm = Wr + (size_t)mat * H * H;
  int c0 = kc * 32 + (l >> 4) * 8;
  int f = ft * 16 + (l & 15);
  ushort16 vals[8];
#pragma unroll
  for (int j = 0; j < 8; ++j) {
    int c = c0 + j;
    float v = (c < H && f < H) ? Wm[c * H + f] : 0.f;
    vals[j] = f2b(v);
  }
  uint4 pk;
  pk.x = (uint32)vals[0] | ((uint32)vals[1] << 16);
  pk.y = (uint32)vals[2] | ((uint32)vals[3] << 16);
  pk.z = (uint32)vals[4] | ((uint32)vals[5] << 16);
  pk.w = (uint32)vals[6] | ((uint32)vals[7] << 16);
  *(uint4*)(Wf + (size_t)b * 512 + l * 8) = pk;
}

// ---------------- MFMA GEMM: C[N,100] (+)= sum_k Tk @ Wk ----------------

__global__ __launch_bounds__(256) void gemm_mfma(const ushort16* __restrict__ Ta, const ushort16* __restrict__ Tb,
                                                 const ushort16* __restrict__ Tc, int nk,
                                                 const ushort16* __restrict__ Wf, const float* __restrict__ bias,
                                                 float* __restrict__ C, int n, int initMode) {
  int t = threadIdx.x;
  int w = t >> 6, l = t & 63;
  int ml = l & 15, quad = l >> 4;
  int n0 = blockIdx.x * 128 + 32 * w;

  f4v acc[2][7];
  if (initMode) {
#pragma unroll
    for (int ft = 0; ft < 7; ++ft) {
      int f = ft * 16 + ml;
      float b = (f < H) ? bias[f] : 0.f;
      f4v v = {b, b, b, b};
      acc[0][ft] = v;
      acc[1][ft] = v;
    }
  } else {
#pragma unroll
    for (int s = 0; s < 2; ++s)
#pragma unroll
      for (int ft = 0; ft < 7; ++ft) {
        int f = ft * 16 + ml;
#pragma unroll
        for (int r = 0; r < 4; ++r) {
          int row = n0 + 16 * s + quad * 4 + r;
          acc[s][ft][r] = (f < H && row < n) ? C[(size_t)row * H + f] : 0.f;
        }
      }
  }

  for (int k = 0; k < nk; ++k) {
    const ushort16* T = (k == 0) ? Ta : ((k == 1) ? Tb : Tc);
#pragma unroll
    for (int kc = 0; kc < 4; ++kc) {
      s8v bfrag[7];
      const ushort16* wb = Wf + ((size_t)(k * 4 + kc) * 7) * 512 + l * 8;
#pragma unroll
      for (int ft = 0; ft < 7; ++ft) bfrag[ft] = *(const s8v*)(wb + ft * 512);
#pragma unroll
      for (int s = 0; s < 2; ++s) {
        const ushort16* ap = T + (size_t)(n0 + 16 * s + ml) * 128 + kc * 32 + quad * 8;
        s8v a = *(const s8v*)ap;
#pragma unroll
        for (int ft = 0; ft < 7; ++ft)
          acc[s][ft] = __builtin_amdgcn_mfma_f32_16x16x32_bf16(a, bfrag[ft], acc[s][ft], 0, 0, 0);
      }
    }
  }

#pragma unroll
  for (int s = 0; s < 2; ++s)
#pragma unroll
    for (int ft = 0; ft < 7; ++ft) {
      int f = ft * 16 + ml;
      if (f < H) {
#pragma unroll
        for (int r = 0; r < 4; ++r) {
          int row = n0 + 16 * s + quad * 4 + r;
          if (row < n) C[(size_t)row * H + f] = acc[s][ft][r];
        }
      }
    }
}

// ---------------- layer 0 dense part ----------------

__global__ __launch_bounds__(128) void layer0_out(const float* __restrict__ x, const float* __restrict__ t1,
                                                  const float* __restrict__ t2, const float* __restrict__ t3,
                                                  const float* __restrict__ t4, const float* __restrict__ W0,
                                                  const float* __restrict__ b0, float* __restrict__ C, int n) {
  int f = threadIdx.x;
  bool act = f < H;
  float w[10];
  float b = 0.f;
  if (act) {
#pragma unroll
    for (int j = 0; j < 10; ++j) w[j] = W0[j * H + f];
    b = b0[f];
  }
  int n0 = blockIdx.x * 32;
  int n1 = n0 + 32 < n ? n0 + 32 : n;
  for (int i = n0; i < n1; ++i) {
    if (!act) continue;
    float acc = b;
    acc = fmaf(x[2 * i],      w[0], acc);
    acc = fmaf(x[2 * i + 1],  w[1], acc);
    acc = fmaf(t1[2 * i],     w[2], acc);
    acc = fmaf(t1[2 * i + 1], w[3], acc);
    acc = fmaf(t2[2 * i],     w[4], acc);
    acc = fmaf(t2[2 * i + 1], w[5], acc);
    acc = fmaf(t3[2 * i],     w[6], acc);
    acc = fmaf(t3[2 * i + 1], w[7], acc);
    acc = fmaf(t4[2 * i],     w[8], acc);
    acc = fmaf(t4[2 * i + 1], w[9], acc);
    C[(size_t)i * H + f] = acc;
  }
}

// ---------------- batch norm ----------------

__global__ __launch_bounds__(128) void bn_stats(const float* __restrict__ acc, float* __restrict__ stats, int n) {
  int f = threadIdx.x;
  int n0 = blockIdx.x * 512;
  int n1 = n0 + 512 < n ? n0 + 512 : n;
  if (f < H) {
    float s = 0.f, s2 = 0.f;
    for (int i = n0; i < n1; ++i) {
      float v = fmaxf(acc[(size_t)i * H + f], 0.f);
      s += v;
      s2 = fmaf(v, v, s2);
    }
    atomicAdd(&stats[f], s);
    atomicAdd(&stats[128 + f], s2);
  }
}

__global__ __launch_bounds__(128) void bn_params(float* __restrict__ stats, const float* __restrict__ gamma,
                                                 const float* __restrict__ beta, int n) {
  int f = threadIdx.x;
  if (f >= H) return;
  float inv_n = 1.f / (float)n;
  float m = stats[f] * inv_n;
  float v = stats[128 + f] * inv_n - m * m;
  float is = rsqrtf(v + 1e-5f);
  float g = gamma[f] * is;
  stats[256 + f] = g;                // scale
  stats[384 + f] = beta[f] - m * g;  // shift
}

// fp32 out (final layer, in-place over C)
__global__ __launch_bounds__(256) void bn_final(const float* __restrict__ acc, const float* __restrict__ mi,
                                                float* __restrict__ out, int total) {
  int idx = blockIdx.x * 256 + threadIdx.x;
  if (idx >= total) return;
  int f = idx % H;
  float v = fmaxf(acc[idx], 0.f);
  out[idx] = fmaf(v, mi[f], mi[128 + f]);
}

// bf16 out with row stride 128 (h for next layer); pads untouched (kept zero by pad_zero/prop_hb)
__global__ __launch_bounds__(256) void bn_final_bf16(const float* __restrict__ acc, const float* __restrict__ mi,
                                                     ushort16* __restrict__ out, int total) {
  int idx = blockIdx.x * 256 + threadIdx.x;
  if (idx >= total) return;
  int row = idx / H, f = idx - row * H;
  float v = fmaxf(acc[idx], 0.f);
  out[(size_t)row * 128 + f] = f2b(fmaf(v, mi[f], mi[128 + f]));
}

// ---------------- launch ----------------

extern "C" void kernel_launch(void* const* d_in, const int* in_sizes, int n_in,
                              void* d_out, int out_size, void* d_ws, size_t ws_size,
                              hipStream_t stream) {
  const float* x     = (const float*)d_in[0];
  const int*   ei    = (const int*)d_in[1];
  const float* W0    = (const float*)d_in[2];
  const float* b0    = (const float*)d_in[3];
  const float* Wr    = (const float*)d_in[4];
  const float* br    = (const float*)d_in[5];
  const float* gamma = (const float*)d_in[6];
  const float* beta  = (const float*)d_in[7];
  float* C = (float*)d_out;

  const int N = in_sizes[0] / FIN;
  const int E = in_sizes[1] / 2;
  const int* src = ei;
  const int* dst = ei + E;

  char* ws = (char*)d_ws;
  size_t off = 0;
  auto alloc = [&](size_t bytes) -> void* {
    void* p = ws + off;
    off = (off + bytes + 255) & ~(size_t)255;
    return p;
  };

  size_t TB = (size_t)N * 128 * sizeof(ushort16);  // bf16, stride-128 rows
  ushort16* B0     = (ushort16*)alloc(TB);
  ushort16* B1     = (ushort16*)alloc(TB);
  ushort16* B2     = (ushort16*)alloc(TB);
  ushort16* Wf     = (ushort16*)alloc((size_t)20 * 14336 * sizeof(ushort16));
  float* t1       = (float*)alloc((size_t)N * 2 * 4);
  float* t2       = (float*)alloc((size_t)N * 2 * 4);
  float* t3       = (float*)alloc((size_t)N * 2 * 4);
  float* t4       = (float*)alloc((size_t)N * 2 * 4);
  float* deg      = (float*)alloc((size_t)N * 4);
  int*   indeg    = (int*)alloc((size_t)N * 4);
  float* dinv     = (float*)alloc((size_t)N * 4);
  int*   incl     = (int*)alloc((size_t)N * 4);
  int*   bsum     = (int*)alloc(8192 * 4);
  int*   bscan    = (int*)alloc(8192 * 4);
  int*   offsets  = (int*)alloc((size_t)(N + 1) * 4);
  int*   cursor   = (int*)alloc((size_t)N * 4);
  int2*  csr      = (int2*)alloc((size_t)E * 8);
  float* stats    = (float*)alloc(512 * 4);

  int gE = (E + 255) / 256;
  int gN = (N + 255) / 256;

  hipMemsetAsync(deg, 0, (size_t)N * 4, stream);
  hipMemsetAsync(indeg, 0, (size_t)N * 4, stream);

  deg_kernel<<<gE, 256, 0, stream>>>(src, dst, deg, indeg, E);
  dinv_kernel<<<gN, 256, 0, stream>>>(deg, dinv, N);
  scan_block<<<gN, 256, 0, stream>>>(indeg, incl, bsum, N);
  scan_sums<<<1, 256, 0, stream>>>(bsum, bscan, gN);
  finalize_offsets<<<gN, 256, 0, stream>>>(incl, indeg, bscan, offsets, cursor, N, E);
  build_csr<<<gE, 256, 0, stream>>>(src, dst, dinv, cursor, csr, E);
  wconv<<<20 * 28, 64, 0, stream>>>(Wr, Wf);
  pad_zero<<<(N * 4 + 255) / 256, 256, 0, stream>>>((uint4*)B0, N);  // B1/B2 pads written by prop_hb

  // ---- layer 0 (F_IN = 2) ----
  prop2<<<gN, 256, 0, stream>>>(x,  x,  t1, offsets, csr, N, 0);
  prop2<<<gN, 256, 0, stream>>>(t1, x,  t2, offsets, csr, N, 1);
  prop2<<<gN, 256, 0, stream>>>(t2, t1, t3, offsets, csr, N, 1);
  prop2<<<gN, 256, 0, stream>>>(t3, t2, t4, offsets, csr, N, 1);
  layer0_out<<<(N + 31) / 32, 128, 0, stream>>>(x, t1, t2, t3, t4, W0, b0, C, N);
  hipMemsetAsync(stats, 0, 1024, stream);
  bn_stats<<<(N + 511) / 512, 128, 0, stream>>>(C, stats, N);
  bn_params<<<1, 128, 0, stream>>>(stats, gamma, beta, N);
  bn_final_bf16<<<(N * H + 255) / 256, 256, 0, stream>>>(C, stats + 256, B0, N * H);

  // ---- layers 1..4 (H = 100, bf16 T buffers, MFMA GEMMs) ----
  int gG = (N + 127) / 128;
  int gP = (N + 3) / 4;
  for (int layer = 1; layer < 5; ++layer) {
    const ushort16* WfL = Wf + (size_t)(layer - 1) * 5 * 14336;
    const float* bl = br + (size_t)(layer - 1) * H;
    // T0 = h (B0); T1 = prop(T0) -> B1; T2 = 2*prop(T1) - T0 -> B2
    prop_hb<<<gP, 256, 0, stream>>>((const uint32*)B0, (const uint32*)B0, (uint32*)B1, offsets, csr, N, 0);
    prop_hb<<<gP, 256, 0, stream>>>((const uint32*)B1, (const uint32*)B0, (uint32*)B2, offsets, csr, N, 1);
    // C = b + T0 W0 + T1 W1 + T2 W2
    gemm_mfma<<<gG, 256, 0, stream>>>(B0, B1, B2, 3, WfL, bl, C, N, 1);
    // T3 = 2*prop(T2) - T1 -> B0 ; T4 = 2*prop(T3) - T2 -> B1
    prop_hb<<<gP, 256, 0, stream>>>((const uint32*)B2, (const uint32*)B1, (uint32*)B0, offsets, csr, N, 1);
    prop_hb<<<gP, 256, 0, stream>>>((const uint32*)B0, (const uint32*)B2, (uint32*)B1, offsets, csr, N, 1);
    // C += T3 W3 + T4 W4
    gemm_mfma<<<gG, 256, 0, stream>>>(B0, B1, B0, 2, WfL + (size_t)3 * 14336, bl, C, N, 0);
    // BN(relu(C)) -> next h (bf16) or final output (fp32)
    hipMemsetAsync(stats, 0, 1024, stream);
    bn_stats<<<(N + 511) / 512, 128, 0, stream>>>(C, stats, N);
    bn_params<<<1, 128, 0, stream>>>(stats, gamma + (size_t)layer * H, beta + (size_t)layer * H, N);
    if (layer < 4)
      bn_final_bf16<<<(N * H + 255) / 256, 256, 0, stream>>>(C, stats + 256, B0, N * H);
    else
      bn_final<<<(N * H + 255) / 256, 256, 0, stream>>>(C, stats + 256, C, N * H);
  }
}

// Round 3
// 5221.426 us; speedup vs baseline: 1.3112x; 1.1147x over previous
//
#include <hip/hip_runtime.h>

#define H 100
#define FIN 2
#define KORD 5
#define NPB 64      // nodes per block in prop_hb2
#define SE_CAP 2048 // LDS-staged CSR entries per block

typedef unsigned int uint32;
typedef unsigned short ushort16;
typedef __attribute__((ext_vector_type(8))) short s8v;   // 8 x bf16 (4 VGPRs)
typedef __attribute__((ext_vector_type(4))) float f4v;   // MFMA accumulator

__device__ __forceinline__ ushort16 f2b(float x) {  // fp32 -> bf16 RNE
  uint32 u = __float_as_uint(x);
  return (ushort16)((u + 0x7fffu + ((u >> 16) & 1u)) >> 16);
}
__device__ __forceinline__ float2 b2f2(uint32 v) {  // packed bf16x2 -> 2 fp32
  return make_float2(__uint_as_float(v << 16), __uint_as_float(v & 0xffff0000u));
}
__device__ __forceinline__ void acc8(float* a, uint4 v, float w) {
  float2 f;
  f = b2f2(v.x); a[0] = fmaf(w, f.x, a[0]); a[1] = fmaf(w, f.y, a[1]);
  f = b2f2(v.y); a[2] = fmaf(w, f.x, a[2]); a[3] = fmaf(w, f.y, a[3]);
  f = b2f2(v.z); a[4] = fmaf(w, f.x, a[4]); a[5] = fmaf(w, f.y, a[5]);
  f = b2f2(v.w); a[6] = fmaf(w, f.x, a[6]); a[7] = fmaf(w, f.y, a[7]);
}

// ---------------- graph setup ----------------

__global__ __launch_bounds__(256) void deg_kernel(const int* __restrict__ src, const int* __restrict__ dst,
                                                  float* __restrict__ deg, int* __restrict__ indeg, int E) {
  int e = blockIdx.x * 256 + threadIdx.x;
  if (e < E) {
    atomicAdd(&deg[src[e]], 1.0f);
    atomicAdd(&indeg[dst[e]], 1);
  }
}

__global__ __launch_bounds__(256) void dinv_kernel(const float* __restrict__ deg, float* __restrict__ dinv, int n) {
  int i = blockIdx.x * 256 + threadIdx.x;
  if (i < n) {
    float d = deg[i];
    dinv[i] = d > 0.f ? rsqrtf(fmaxf(d, 1.f)) : 0.f;
  }
}

__global__ __launch_bounds__(256) void scan_block(const int* __restrict__ in, int* __restrict__ incl,
                                                  int* __restrict__ bsum, int n) {
  __shared__ int s[256];
  int i = blockIdx.x * 256 + threadIdx.x;
  int v = (i < n) ? in[i] : 0;
  s[threadIdx.x] = v;
  __syncthreads();
  for (int d = 1; d < 256; d <<= 1) {
    int t = (threadIdx.x >= d) ? s[threadIdx.x - d] : 0;
    __syncthreads();
    s[threadIdx.x] += t;
    __syncthreads();
  }
  if (i < n) incl[i] = s[threadIdx.x];
  if (threadIdx.x == 255) bsum[blockIdx.x] = s[255];
}

__global__ __launch_bounds__(256) void scan_sums(const int* __restrict__ bsum, int* __restrict__ bscan, int nb) {
  __shared__ int s[256];
  __shared__ int carry;
  if (threadIdx.x == 0) carry = 0;
  __syncthreads();
  for (int base = 0; base < nb; base += 256) {
    int i = base + threadIdx.x;
    int v = (i < nb) ? bsum[i] : 0;
    s[threadIdx.x] = v;
    __syncthreads();
    for (int d = 1; d < 256; d <<= 1) {
      int t = (threadIdx.x >= d) ? s[threadIdx.x - d] : 0;
      __syncthreads();
      s[threadIdx.x] += t;
      __syncthreads();
    }
    int c = carry;
    if (i < nb) bscan[i] = s[threadIdx.x] + c;
    __syncthreads();
    if (threadIdx.x == 0) carry = c + s[255];
    __syncthreads();
  }
}

__global__ __launch_bounds__(256) void finalize_offsets(const int* __restrict__ incl, const int* __restrict__ indeg,
                                                        const int* __restrict__ bscan, int* __restrict__ offsets,
                                                        int* __restrict__ cursor, int n, int total) {
  int i = blockIdx.x * 256 + threadIdx.x;
  if (i < n) {
    int prev = (blockIdx.x > 0) ? bscan[blockIdx.x - 1] : 0;
    int excl = incl[i] - indeg[i] + prev;
    offsets[i] = excl;
    cursor[i] = excl;
  }
  if (i == 0) offsets[n] = total;
}

// CSR entry packed (src, norm-bits): one 8B scattered store instead of two 4B stores.
__global__ __launch_bounds__(256) void build_csr(const int* __restrict__ src, const int* __restrict__ dst,
                                                 const float* __restrict__ dinv, int* __restrict__ cursor,
                                                 int2* __restrict__ csr, int E) {
  int e = blockIdx.x * 256 + threadIdx.x;
  if (e < E) {
    int s = src[e], d = dst[e];
    float nrm = -dinv[s] * dinv[d];
    int p = atomicAdd(&cursor[d], 1);
    csr[p] = make_int2(s, __float_as_int(nrm));
  }
}

// Zero the pad quads (uint32 48..63 = bf16 features 96..127) of row-stride-128 bf16 buffer.
__global__ __launch_bounds__(256) void pad_zero(uint4* __restrict__ b, int nrows) {
  int i = blockIdx.x * 256 + threadIdx.x;
  if (i < nrows * 4) {
    uint4 z; z.x = 0; z.y = 0; z.z = 0; z.w = 0;
    b[(size_t)(i >> 2) * 16 + 12 + (i & 3)] = z;
  }
}

// ---------------- propagate ----------------

// F=2 props for layer 0 (thread per node), 4x unrolled
__global__ __launch_bounds__(256) void prop2(const float* __restrict__ h, const float* __restrict__ prev,
                                             float* __restrict__ out, const int* __restrict__ offs,
                                             const int2* __restrict__ csr, int n, int mode) {
  int i = blockIdx.x * 256 + threadIdx.x;
  if (i >= n) return;
  float a0 = 0.f, a1 = 0.f;
  int e0 = offs[i], e1 = offs[i + 1];
  int e = e0;
  for (; e + 4 <= e1; e += 4) {
    int2 c0 = csr[e], c1 = csr[e + 1], c2 = csr[e + 2], c3 = csr[e + 3];
    float w0 = __int_as_float(c0.y), w1 = __int_as_float(c1.y);
    float w2 = __int_as_float(c2.y), w3 = __int_as_float(c3.y);
    float x0 = h[2 * c0.x], y0 = h[2 * c0.x + 1];
    float x1 = h[2 * c1.x], y1 = h[2 * c1.x + 1];
    float x2 = h[2 * c2.x], y2 = h[2 * c2.x + 1];
    float x3 = h[2 * c3.x], y3 = h[2 * c3.x + 1];
    a0 = fmaf(w0, x0, a0); a1 = fmaf(w0, y0, a1);
    a0 = fmaf(w1, x1, a0); a1 = fmaf(w1, y1, a1);
    a0 = fmaf(w2, x2, a0); a1 = fmaf(w2, y2, a1);
    a0 = fmaf(w3, x3, a0); a1 = fmaf(w3, y3, a1);
  }
  for (; e < e1; ++e) {
    int2 c = csr[e];
    float w = __int_as_float(c.y);
    a0 = fmaf(w, h[2 * c.x], a0);
    a1 = fmaf(w, h[2 * c.x + 1], a1);
  }
  if (mode) {
    a0 = 2.f * a0 - prev[2 * i];
    a1 = 2.f * a1 - prev[2 * i + 1];
  }
  out[2 * i] = a0;
  out[2 * i + 1] = a1;
}

// bf16 prop v2: block = 256 thr handles 64 consecutive nodes. Their CSR ranges are
// CONTIGUOUS, so offs[65] + the whole csr segment (avg 512, cap 2048 entries) are staged
// into LDS with coalesced loads. Each wave then processes 16 nodes; per-round edge
// (src,norm) comes from an LDS broadcast read (no global csr latency, no shfl chain).
// 4 edge-groups x 2 slots = 8 edges (2x256B gathers) in flight per round per wave.
// Cross-group reduce via 2x shfl_xor; group 0 writes the 256B row (pads exact zero).
__global__ __launch_bounds__(256) void prop_hb2(const uint32* __restrict__ h, const uint32* __restrict__ prev,
                                                uint32* __restrict__ out, const int* __restrict__ offs,
                                                const int2* __restrict__ csr, int n, int mode) {
  __shared__ int2 se[SE_CAP];
  __shared__ int soff[NPB + 1];
  int t = threadIdx.x;
  int n0 = blockIdx.x * NPB;
  if (t <= NPB) {
    int idx = n0 + t;
    soff[t] = offs[idx < n ? idx : n];
  }
  __syncthreads();
  int e0b = soff[0], e1b = soff[NPB];
  bool staged = (e1b - e0b) <= SE_CAP;
  if (staged) {
    for (int i = e0b + t; i < e1b; i += 256) se[i - e0b] = csr[i];
  }
  __syncthreads();

  int w = t >> 6, lane = t & 63, grp = lane >> 4, sub = lane & 15;
  const uint4* hq = (const uint4*)h;
  uint4* oq = (uint4*)out;
  bool wr = (grp == 0);

  for (int ni = 0; ni < 16; ++ni) {
    int node = n0 + w * 16 + ni;
    if (node >= n) break;
    int li = w * 16 + ni;
    int e0 = soff[li], e1 = soff[li + 1];
    int deg = e1 - e0;
    size_t qi = (size_t)node * 16 + sub;

    uint4 pv; pv.x = 0; pv.y = 0; pv.z = 0; pv.w = 0;
    if (mode && wr && sub < 13) pv = ((const uint4*)prev)[qi];  // issue early, overlaps gathers

    float a[8];
#pragma unroll
    for (int j = 0; j < 8; ++j) a[j] = 0.f;

    int nr = (deg + 7) >> 3;
    if (staged) {
      int eb = e0 - e0b;
      for (int r = 0; r < nr; ++r) {
        int ea = 8 * r + grp;
        int2 ca = (ea < deg) ? se[eb + ea] : make_int2(0, 0);
        int2 cb = (ea + 4 < deg) ? se[eb + ea + 4] : make_int2(0, 0);
        uint4 va = hq[(size_t)ca.x * 16 + sub];
        uint4 vb = hq[(size_t)cb.x * 16 + sub];
        acc8(a, va, __int_as_float(ca.y));
        acc8(a, vb, __int_as_float(cb.y));
      }
    } else {  // freak block with >SE_CAP edges: direct global csr (broadcast reads)
      const int2* cp = csr + e0;
      for (int r = 0; r < nr; ++r) {
        int ea = 8 * r + grp;
        int2 ca = (ea < deg) ? cp[ea] : make_int2(0, 0);
        int2 cb = (ea + 4 < deg) ? cp[ea + 4] : make_int2(0, 0);
        uint4 va = hq[(size_t)ca.x * 16 + sub];
        uint4 vb = hq[(size_t)cb.x * 16 + sub];
        acc8(a, va, __int_as_float(ca.y));
        acc8(a, vb, __int_as_float(cb.y));
      }
    }

    // reduce partial sums across the 4 edge-groups
#pragma unroll
    for (int j = 0; j < 8; ++j) a[j] += __shfl_xor(a[j], 16);
#pragma unroll
    for (int j = 0; j < 8; ++j) a[j] += __shfl_xor(a[j], 32);

    if (!wr) continue;  // group 0 writes the full row: 16 lanes x 16B = 256B coalesced
    if (sub >= 13) {    // pure pad quads (features 104..127): keep exact zero
      uint4 z; z.x = 0; z.y = 0; z.z = 0; z.w = 0;
      oq[qi] = z;
      continue;
    }
    if (sub == 12) { a[4] = 0.f; a[5] = 0.f; a[6] = 0.f; a[7] = 0.f; }  // features 100..103 = pad
    float rr[8];
    if (mode) {  // out = 2*prop - prev ; prev pads are zero so pads stay exactly zero
      float2 p;
      p = b2f2(pv.x); rr[0] = 2.f * a[0] - p.x; rr[1] = 2.f * a[1] - p.y;
      p = b2f2(pv.y); rr[2] = 2.f * a[2] - p.x; rr[3] = 2.f * a[3] - p.y;
      p = b2f2(pv.z); rr[4] = 2.f * a[4] - p.x; rr[5] = 2.f * a[5] - p.y;
      p = b2f2(pv.w); rr[6] = 2.f * a[6] - p.x; rr[7] = 2.f * a[7] - p.y;
    } else {
#pragma unroll
      for (int j = 0; j < 8; ++j) rr[j] = a[j];
    }
    uint4 pk;
    pk.x = (uint32)f2b(rr[0]) | ((uint32)f2b(rr[1]) << 16);
    pk.y = (uint32)f2b(rr[2]) | ((uint32)f2b(rr[3]) << 16);
    pk.z = (uint32)f2b(rr[4]) | ((uint32)f2b(rr[5]) << 16);
    pk.w = (uint32)f2b(rr[6]) | ((uint32)f2b(rr[7]) << 16);
    oq[qi] = pk;
  }
}

// ---------------- W repack: fp32 [mat][c][f] -> bf16 MFMA B-fragments ----------------

__global__ __launch_bounds__(64) void wconv(const float* __restrict__ Wr, ushort16* __restrict__ Wf) {
  int b = blockIdx.x;
  int l = threadIdx.x;
  int mat = b / 28, rem = b % 28;
  int kc = rem / 7, ft = rem % 7;
  const float* Wm = Wr + (size_t)mat * H * H;
  int c0 = kc * 32 + (l >> 4) * 8;
  int f = ft * 16 + (l & 15);
  ushort16 vals[8];
#pragma unroll
  for (int j = 0; j < 8; ++j) {
    int c = c0 + j;
    float v = (c < H && f < H) ? Wm[c * H + f] : 0.f;
    vals[j] = f2b(v);
  }
  uint4 pk;
  pk.x = (uint32)vals[0] | ((uint32)vals[1] << 16);
  pk.y = (uint32)vals[2] | ((uint32)vals[3] << 16);
  pk.z = (uint32)vals[4] | ((uint32)vals[5] << 16);
  pk.w = (uint32)vals[6] | ((uint32)vals[7] << 16);
  *(uint4*)(Wf + (size_t)b * 512 + l * 8) = pk;
}

// ---------------- MFMA GEMM: C[N,100] (+)= sum_k Tk @ Wk, up to 5 T operands ----------------

__global__ __launch_bounds__(256) void gemm_mfma(const ushort16* __restrict__ Ta, const ushort16* __restrict__ Tb,
                                                 const ushort16* __restrict__ Tc, const ushort16* __restrict__ Td,
                                                 const ushort16* __restrict__ Te, int nk,
                                                 const ushort16* __restrict__ Wf, const float* __restrict__ bias,
                                                 float* __restrict__ C, int n, int initMode) {
  int t = threadIdx.x;
  int w = t >> 6, l = t & 63;
  int ml = l & 15, quad = l >> 4;
  int n0 = blockIdx.x * 128 + 32 * w;

  f4v acc[2][7];
  if (initMode) {
#pragma unroll
    for (int ft = 0; ft < 7; ++ft) {
      int f = ft * 16 + ml;
      float b = (f < H) ? bias[f] : 0.f;
      f4v v = {b, b, b, b};
      acc[0][ft] = v;
      acc[1][ft] = v;
    }
  } else {
#pragma unroll
    for (int s = 0; s < 2; ++s)
#pragma unroll
      for (int ft = 0; ft < 7; ++ft) {
        int f = ft * 16 + ml;
#pragma unroll
        for (int r = 0; r < 4; ++r) {
          int row = n0 + 16 * s + quad * 4 + r;
          acc[s][ft][r] = (f < H && row < n) ? C[(size_t)row * H + f] : 0.f;
        }
      }
  }

  for (int k = 0; k < nk; ++k) {
    const ushort16* T = (k == 0) ? Ta : (k == 1) ? Tb : (k == 2) ? Tc : (k == 3) ? Td : Te;
#pragma unroll
    for (int kc = 0; kc < 4; ++kc) {
      s8v bfrag[7];
      const ushort16* wb = Wf + ((size_t)(k * 4 + kc) * 7) * 512 + l * 8;
#pragma unroll
      for (int ft = 0; ft < 7; ++ft) bfrag[ft] = *(const s8v*)(wb + ft * 512);
#pragma unroll
      for (int s = 0; s < 2; ++s) {
        const ushort16* ap = T + (size_t)(n0 + 16 * s + ml) * 128 + kc * 32 + quad * 8;
        s8v a = *(const s8v*)ap;
#pragma unroll
        for (int ft = 0; ft < 7; ++ft)
          acc[s][ft] = __builtin_amdgcn_mfma_f32_16x16x32_bf16(a, bfrag[ft], acc[s][ft], 0, 0, 0);
      }
    }
  }

#pragma unroll
  for (int s = 0; s < 2; ++s)
#pragma unroll
    for (int ft = 0; ft < 7; ++ft) {
      int f = ft * 16 + ml;
      if (f < H) {
#pragma unroll
        for (int r = 0; r < 4; ++r) {
          int row = n0 + 16 * s + quad * 4 + r;
          if (row < n) C[(size_t)row * H + f] = acc[s][ft][r];
        }
      }
    }
}

// ---------------- layer 0 dense part ----------------

__global__ __launch_bounds__(128) void layer0_out(const float* __restrict__ x, const float* __restrict__ t1,
                                                  const float* __restrict__ t2, const float* __restrict__ t3,
                                                  const float* __restrict__ t4, const float* __restrict__ W0,
                                                  const float* __restrict__ b0, float* __restrict__ C, int n) {
  int f = threadIdx.x;
  bool act = f < H;
  float w[10];
  float b = 0.f;
  if (act) {
#pragma unroll
    for (int j = 0; j < 10; ++j) w[j] = W0[j * H + f];
    b = b0[f];
  }
  int n0 = blockIdx.x * 32;
  int n1 = n0 + 32 < n ? n0 + 32 : n;
  for (int i = n0; i < n1; ++i) {
    if (!act) continue;
    float acc = b;
    acc = fmaf(x[2 * i],      w[0], acc);
    acc = fmaf(x[2 * i + 1],  w[1], acc);
    acc = fmaf(t1[2 * i],     w[2], acc);
    acc = fmaf(t1[2 * i + 1], w[3], acc);
    acc = fmaf(t2[2 * i],     w[4], acc);
    acc = fmaf(t2[2 * i + 1], w[5], acc);
    acc = fmaf(t3[2 * i],     w[6], acc);
    acc = fmaf(t3[2 * i + 1], w[7], acc);
    acc = fmaf(t4[2 * i],     w[8], acc);
    acc = fmaf(t4[2 * i + 1], w[9], acc);
    C[(size_t)i * H + f] = acc;
  }
}

// ---------------- batch norm ----------------

__global__ __launch_bounds__(128) void bn_stats(const float* __restrict__ acc, float* __restrict__ stats, int n) {
  int f = threadIdx.x;
  int n0 = blockIdx.x * 512;
  int n1 = n0 + 512 < n ? n0 + 512 : n;
  if (f < H) {
    float s = 0.f, s2 = 0.f;
    for (int i = n0; i < n1; ++i) {
      float v = fmaxf(acc[(size_t)i * H + f], 0.f);
      s += v;
      s2 = fmaf(v, v, s2);
    }
    atomicAdd(&stats[f], s);
    atomicAdd(&stats[128 + f], s2);
  }
}

__global__ __launch_bounds__(128) void bn_params(float* __restrict__ stats, const float* __restrict__ gamma,
                                                 const float* __restrict__ beta, int n) {
  int f = threadIdx.x;
  if (f >= H) return;
  float inv_n = 1.f / (float)n;
  float m = stats[f] * inv_n;
  float v = stats[128 + f] * inv_n - m * m;
  float is = rsqrtf(v + 1e-5f);
  float g = gamma[f] * is;
  stats[256 + f] = g;                // scale
  stats[384 + f] = beta[f] - m * g;  // shift
}

// fp32 out (final layer, in-place over C)
__global__ __launch_bounds__(256) void bn_final(const float* __restrict__ acc, const float* __restrict__ mi,
                                                float* __restrict__ out, int total) {
  int idx = blockIdx.x * 256 + threadIdx.x;
  if (idx >= total) return;
  int f = idx % H;
  float v = fmaxf(acc[idx], 0.f);
  out[idx] = fmaf(v, mi[f], mi[128 + f]);
}

// bf16 out with row stride 128 (h for next layer); pads untouched (kept zero by pad_zero/prop_hb2)
__global__ __launch_bounds__(256) void bn_final_bf16(const float* __restrict__ acc, const float* __restrict__ mi,
                                                     ushort16* __restrict__ out, int total) {
  int idx = blockIdx.x * 256 + threadIdx.x;
  if (idx >= total) return;
  int row = idx / H, f = idx - row * H;
  float v = fmaxf(acc[idx], 0.f);
  out[(size_t)row * 128 + f] = f2b(fmaf(v, mi[f], mi[128 + f]));
}

// ---------------- launch ----------------

extern "C" void kernel_launch(void* const* d_in, const int* in_sizes, int n_in,
                              void* d_out, int out_size, void* d_ws, size_t ws_size,
                              hipStream_t stream) {
  const float* x     = (const float*)d_in[0];
  const int*   ei    = (const int*)d_in[1];
  const float* W0    = (const float*)d_in[2];
  const float* b0    = (const float*)d_in[3];
  const float* Wr    = (const float*)d_in[4];
  const float* br    = (const float*)d_in[5];
  const float* gamma = (const float*)d_in[6];
  const float* beta  = (const float*)d_in[7];
  float* C = (float*)d_out;

  const int N = in_sizes[0] / FIN;
  const int E = in_sizes[1] / 2;
  const int* src = ei;
  const int* dst = ei + E;

  char* ws = (char*)d_ws;
  size_t off = 0;
  auto alloc = [&](size_t bytes) -> void* {
    void* p = ws + off;
    off = (off + bytes + 255) & ~(size_t)255;
    return p;
  };

  size_t TB = (size_t)N * 128 * sizeof(ushort16);  // bf16, stride-128 rows
  ushort16* B0     = (ushort16*)alloc(TB);
  ushort16* B1     = (ushort16*)alloc(TB);
  ushort16* B2     = (ushort16*)alloc(TB);
  ushort16* Wf     = (ushort16*)alloc((size_t)20 * 14336 * sizeof(ushort16));
  float* t1       = (float*)alloc((size_t)N * 2 * 4);
  float* t2       = (float*)alloc((size_t)N * 2 * 4);
  float* t3       = (float*)alloc((size_t)N * 2 * 4);
  float* t4       = (float*)alloc((size_t)N * 2 * 4);
  float* deg      = (float*)alloc((size_t)N * 4);
  int*   indeg    = (int*)alloc((size_t)N * 4);
  float* dinv     = (float*)alloc((size_t)N * 4);
  int*   incl     = (int*)alloc((size_t)N * 4);
  int*   bsum     = (int*)alloc(8192 * 4);
  int*   bscan    = (int*)alloc(8192 * 4);
  int*   offsets  = (int*)alloc((size_t)(N + 1) * 4);
  int*   cursor   = (int*)alloc((size_t)N * 4);
  int2*  csr      = (int2*)alloc((size_t)E * 8);
  float* stats    = (float*)alloc(512 * 4);

  // Two extra T buffers (single-gemm-per-layer path) if workspace allows.
  ushort16* B3 = B0;
  ushort16* B4 = B1;
  bool five = (off + 2 * TB + 512 <= ws_size);
  if (five) {
    B3 = (ushort16*)alloc(TB);
    B4 = (ushort16*)alloc(TB);
  }

  int gE = (E + 255) / 256;
  int gN = (N + 255) / 256;

  hipMemsetAsync(deg, 0, (size_t)N * 4, stream);
  hipMemsetAsync(indeg, 0, (size_t)N * 4, stream);

  deg_kernel<<<gE, 256, 0, stream>>>(src, dst, deg, indeg, E);
  dinv_kernel<<<gN, 256, 0, stream>>>(deg, dinv, N);
  scan_block<<<gN, 256, 0, stream>>>(indeg, incl, bsum, N);
  scan_sums<<<1, 256, 0, stream>>>(bsum, bscan, gN);
  finalize_offsets<<<gN, 256, 0, stream>>>(incl, indeg, bscan, offsets, cursor, N, E);
  build_csr<<<gE, 256, 0, stream>>>(src, dst, dinv, cursor, csr, E);
  wconv<<<20 * 28, 64, 0, stream>>>(Wr, Wf);
  pad_zero<<<(N * 4 + 255) / 256, 256, 0, stream>>>((uint4*)B0, N);  // other B pads written by prop_hb2

  // ---- layer 0 (F_IN = 2) ----
  prop2<<<gN, 256, 0, stream>>>(x,  x,  t1, offsets, csr, N, 0);
  prop2<<<gN, 256, 0, stream>>>(t1, x,  t2, offsets, csr, N, 1);
  prop2<<<gN, 256, 0, stream>>>(t2, t1, t3, offsets, csr, N, 1);
  prop2<<<gN, 256, 0, stream>>>(t3, t2, t4, offsets, csr, N, 1);
  layer0_out<<<(N + 31) / 32, 128, 0, stream>>>(x, t1, t2, t3, t4, W0, b0, C, N);
  hipMemsetAsync(stats, 0, 1024, stream);
  bn_stats<<<(N + 511) / 512, 128, 0, stream>>>(C, stats, N);
  bn_params<<<1, 128, 0, stream>>>(stats, gamma, beta, N);
  bn_final_bf16<<<(N * H + 255) / 256, 256, 0, stream>>>(C, stats + 256, B0, N * H);

  // ---- layers 1..4 (H = 100, bf16 T buffers, MFMA GEMMs) ----
  int gG = (N + 127) / 128;
  int gP = (N + NPB - 1) / NPB;
  for (int layer = 1; layer < 5; ++layer) {
    const ushort16* WfL = Wf + (size_t)(layer - 1) * 5 * 14336;
    const float* bl = br + (size_t)(layer - 1) * H;
    if (five) {
      // T1..T4 into B1..B4, then one gemm over all 5 Chebyshev terms
      prop_hb2<<<gP, 256, 0, stream>>>((const uint32*)B0, (const uint32*)B0, (uint32*)B1, offsets, csr, N, 0);
      prop_hb2<<<gP, 256, 0, stream>>>((const uint32*)B1, (const uint32*)B0, (uint32*)B2, offsets, csr, N, 1);
      prop_hb2<<<gP, 256, 0, stream>>>((const uint32*)B2, (const uint32*)B1, (uint32*)B3, offsets, csr, N, 1);
      prop_hb2<<<gP, 256, 0, stream>>>((const uint32*)B3, (const uint32*)B2, (uint32*)B4, offsets, csr, N, 1);
      gemm_mfma<<<gG, 256, 0, stream>>>(B0, B1, B2, B3, B4, 5, WfL, bl, C, N, 1);
    } else {
      prop_hb2<<<gP, 256, 0, stream>>>((const uint32*)B0, (const uint32*)B0, (uint32*)B1, offsets, csr, N, 0);
      prop_hb2<<<gP, 256, 0, stream>>>((const uint32*)B1, (const uint32*)B0, (uint32*)B2, offsets, csr, N, 1);
      gemm_mfma<<<gG, 256, 0, stream>>>(B0, B1, B2, B0, B1, 3, WfL, bl, C, N, 1);
      prop_hb2<<<gP, 256, 0, stream>>>((const uint32*)B2, (const uint32*)B1, (uint32*)B0, offsets, csr, N, 1);
      prop_hb2<<<gP, 256, 0, stream>>>((const uint32*)B0, (const uint32*)B2, (uint32*)B1, offsets, csr, N, 1);
      gemm_mfma<<<gG, 256, 0, stream>>>(B0, B1, B0, B0, B1, 2, WfL + (size_t)3 * 14336, bl, C, N, 0);
    }
    // BN(relu(C)) -> next h (bf16) or final output (fp32)
    hipMemsetAsync(stats, 0, 1024, stream);
    bn_stats<<<(N + 511) / 512, 128, 0, stream>>>(C, stats, N);
    bn_params<<<1, 128, 0, stream>>>(stats, gamma + (size_t)layer * H, beta + (size_t)layer * H, N);
    if (layer < 4)
      bn_final_bf16<<<(N * H + 255) / 256, 256, 0, stream>>>(C, stats + 256, B0, N * H);
    else
      bn_final<<<(N * H + 255) / 256, 256, 0, stream>>>(C, stats + 256, C, N * H);
  }
}

// Round 4
// 4914.907 us; speedup vs baseline: 1.3930x; 1.0624x over previous
//
#include <hip/hip_runtime.h>

#define H 100
#define FIN 2
#define KORD 5
#define NPB 64      // nodes per block in prop_hb3
#define SE_CAP 2048 // LDS-staged CSR entries per block

typedef unsigned int uint32;
typedef unsigned short ushort16;
typedef __attribute__((ext_vector_type(8))) short s8v;   // 8 x bf16 (4 VGPRs)
typedef __attribute__((ext_vector_type(4))) float f4v;   // MFMA accumulator

__device__ __forceinline__ ushort16 f2b(float x) {  // fp32 -> bf16 RNE
  uint32 u = __float_as_uint(x);
  return (ushort16)((u + 0x7fffu + ((u >> 16) & 1u)) >> 16);
}
__device__ __forceinline__ float2 b2f2(uint32 v) {  // packed bf16x2 -> 2 fp32
  return make_float2(__uint_as_float(v << 16), __uint_as_float(v & 0xffff0000u));
}
__device__ __forceinline__ void acc8(float* a, uint4 v, float w) {
  float2 f;
  f = b2f2(v.x); a[0] = fmaf(w, f.x, a[0]); a[1] = fmaf(w, f.y, a[1]);
  f = b2f2(v.y); a[2] = fmaf(w, f.x, a[2]); a[3] = fmaf(w, f.y, a[3]);
  f = b2f2(v.z); a[4] = fmaf(w, f.x, a[4]); a[5] = fmaf(w, f.y, a[5]);
  f = b2f2(v.w); a[6] = fmaf(w, f.x, a[6]); a[7] = fmaf(w, f.y, a[7]);
}

// ---------------- graph setup ----------------

__global__ __launch_bounds__(256) void deg_kernel(const int* __restrict__ src, const int* __restrict__ dst,
                                                  float* __restrict__ deg, int* __restrict__ indeg, int E) {
  int e = blockIdx.x * 256 + threadIdx.x;
  if (e < E) {
    atomicAdd(&deg[src[e]], 1.0f);
    atomicAdd(&indeg[dst[e]], 1);
  }
}

__global__ __launch_bounds__(256) void dinv_kernel(const float* __restrict__ deg, float* __restrict__ dinv, int n) {
  int i = blockIdx.x * 256 + threadIdx.x;
  if (i < n) {
    float d = deg[i];
    dinv[i] = d > 0.f ? rsqrtf(fmaxf(d, 1.f)) : 0.f;
  }
}

__global__ __launch_bounds__(256) void scan_block(const int* __restrict__ in, int* __restrict__ incl,
                                                  int* __restrict__ bsum, int n) {
  __shared__ int s[256];
  int i = blockIdx.x * 256 + threadIdx.x;
  int v = (i < n) ? in[i] : 0;
  s[threadIdx.x] = v;
  __syncthreads();
  for (int d = 1; d < 256; d <<= 1) {
    int t = (threadIdx.x >= d) ? s[threadIdx.x - d] : 0;
    __syncthreads();
    s[threadIdx.x] += t;
    __syncthreads();
  }
  if (i < n) incl[i] = s[threadIdx.x];
  if (threadIdx.x == 255) bsum[blockIdx.x] = s[255];
}

__global__ __launch_bounds__(256) void scan_sums(const int* __restrict__ bsum, int* __restrict__ bscan, int nb) {
  __shared__ int s[256];
  __shared__ int carry;
  if (threadIdx.x == 0) carry = 0;
  __syncthreads();
  for (int base = 0; base < nb; base += 256) {
    int i = base + threadIdx.x;
    int v = (i < nb) ? bsum[i] : 0;
    s[threadIdx.x] = v;
    __syncthreads();
    for (int d = 1; d < 256; d <<= 1) {
      int t = (threadIdx.x >= d) ? s[threadIdx.x - d] : 0;
      __syncthreads();
      s[threadIdx.x] += t;
      __syncthreads();
    }
    int c = carry;
    if (i < nb) bscan[i] = s[threadIdx.x] + c;
    __syncthreads();
    if (threadIdx.x == 0) carry = c + s[255];
    __syncthreads();
  }
}

__global__ __launch_bounds__(256) void finalize_offsets(const int* __restrict__ incl, const int* __restrict__ indeg,
                                                        const int* __restrict__ bscan, int* __restrict__ offsets,
                                                        int* __restrict__ cursor, int n, int total) {
  int i = blockIdx.x * 256 + threadIdx.x;
  if (i < n) {
    int prev = (blockIdx.x > 0) ? bscan[blockIdx.x - 1] : 0;
    int excl = incl[i] - indeg[i] + prev;
    offsets[i] = excl;
    cursor[i] = excl;
  }
  if (i == 0) offsets[n] = total;
}

// CSR entry packed (src, norm-bits): one 8B scattered store instead of two 4B stores.
__global__ __launch_bounds__(256) void build_csr(const int* __restrict__ src, const int* __restrict__ dst,
                                                 const float* __restrict__ dinv, int* __restrict__ cursor,
                                                 int2* __restrict__ csr, int E) {
  int e = blockIdx.x * 256 + threadIdx.x;
  if (e < E) {
    int s = src[e], d = dst[e];
    float nrm = -dinv[s] * dinv[d];
    int p = atomicAdd(&cursor[d], 1);
    csr[p] = make_int2(s, __float_as_int(nrm));
  }
}

// Zero the pad quads (uint32 48..63 = bf16 features 96..127) of row-stride-128 bf16 buffer.
__global__ __launch_bounds__(256) void pad_zero(uint4* __restrict__ b, int nrows) {
  int i = blockIdx.x * 256 + threadIdx.x;
  if (i < nrows * 4) {
    uint4 z; z.x = 0; z.y = 0; z.z = 0; z.w = 0;
    b[(size_t)(i >> 2) * 16 + 12 + (i & 3)] = z;
  }
}

// ---------------- propagate ----------------

// F=2 props for layer 0 (thread per node), 4x unrolled
__global__ __launch_bounds__(256) void prop2(const float* __restrict__ h, const float* __restrict__ prev,
                                             float* __restrict__ out, const int* __restrict__ offs,
                                             const int2* __restrict__ csr, int n, int mode) {
  int i = blockIdx.x * 256 + threadIdx.x;
  if (i >= n) return;
  float a0 = 0.f, a1 = 0.f;
  int e0 = offs[i], e1 = offs[i + 1];
  int e = e0;
  for (; e + 4 <= e1; e += 4) {
    int2 c0 = csr[e], c1 = csr[e + 1], c2 = csr[e + 2], c3 = csr[e + 3];
    float w0 = __int_as_float(c0.y), w1 = __int_as_float(c1.y);
    float w2 = __int_as_float(c2.y), w3 = __int_as_float(c3.y);
    float x0 = h[2 * c0.x], y0 = h[2 * c0.x + 1];
    float x1 = h[2 * c1.x], y1 = h[2 * c1.x + 1];
    float x2 = h[2 * c2.x], y2 = h[2 * c2.x + 1];
    float x3 = h[2 * c3.x], y3 = h[2 * c3.x + 1];
    a0 = fmaf(w0, x0, a0); a1 = fmaf(w0, y0, a1);
    a0 = fmaf(w1, x1, a0); a1 = fmaf(w1, y1, a1);
    a0 = fmaf(w2, x2, a0); a1 = fmaf(w2, y2, a1);
    a0 = fmaf(w3, x3, a0); a1 = fmaf(w3, y3, a1);
  }
  for (; e < e1; ++e) {
    int2 c = csr[e];
    float w = __int_as_float(c.y);
    a0 = fmaf(w, h[2 * c.x], a0);
    a1 = fmaf(w, h[2 * c.x + 1], a1);
  }
  if (mode) {
    a0 = 2.f * a0 - prev[2 * i];
    a1 = 2.f * a1 - prev[2 * i + 1];
  }
  out[2 * i] = a0;
  out[2 * i + 1] = a1;
}

// bf16 prop v3: LDS-staged CSR (as v2) + 2-deep software pipeline over a flat (node,round)
// task stream. Each round = 8 edges (2 x 1KB gathers: 4 edges per 16-lane group x 2 slots).
// The NEXT task's gathers are issued before consuming the current ones, and the per-node
// reduce/pack/store tail overlaps the next node's in-flight gathers. Doubles in-flight
// cache lines per wave (32 -> 64) and removes the tail from the latency chain.
__global__ __launch_bounds__(256) void prop_hb3(const uint32* __restrict__ h, const uint32* __restrict__ prev,
                                                uint32* __restrict__ out, const int* __restrict__ offs,
                                                const int2* __restrict__ csr, int n, int mode) {
  __shared__ int2 se[SE_CAP];
  __shared__ int soff[NPB + 1];
  int t = threadIdx.x;
  int n0 = blockIdx.x * NPB;
  if (t <= NPB) {
    int idx = n0 + t;
    soff[t] = offs[idx < n ? idx : n];
  }
  __syncthreads();
  int e0b = soff[0], e1b = soff[NPB];
  bool staged = (e1b - e0b) <= SE_CAP;
  if (staged) {
    for (int i = e0b + t; i < e1b; i += 256) se[i - e0b] = csr[i];
  }
  __syncthreads();

  int w = t >> 6, lane = t & 63, grp = lane >> 4, sub = lane & 15;
  const uint4* hq = (const uint4*)h;
  uint4* oq = (uint4*)out;
  bool wr = (grp == 0);
  int base = w * 16;
  int cnt = 16;
  if (n0 + base + 16 > n) cnt = n - (n0 + base);
  if (cnt <= 0) return;

  auto nrOf = [&](int li) {
    int d = soff[base + li + 1] - soff[base + li];
    int r = (d + 7) >> 3;
    return r ? r : 1;
  };
  auto issueLoads = [&](int li, int r, uint4& v0, uint4& v1, float& w0, float& w1) {
    int e0 = soff[base + li];
    int deg = soff[base + li + 1] - e0;
    int ea = 8 * r + grp;
    int2 ca = make_int2(0, 0), cb = make_int2(0, 0);
    if (staged) {
      int eb = e0 - e0b;
      if (ea < deg) ca = se[eb + ea];
      if (ea + 4 < deg) cb = se[eb + ea + 4];
    } else {
      if (ea < deg) ca = csr[e0 + ea];
      if (ea + 4 < deg) cb = csr[e0 + ea + 4];
    }
    v0 = hq[(size_t)ca.x * 16 + sub];
    v1 = hq[(size_t)cb.x * 16 + sub];
    w0 = __int_as_float(ca.y);
    w1 = __int_as_float(cb.y);
  };
  auto finishNode = [&](int li, float* a) {
    int node = n0 + base + li;
    size_t qi = (size_t)node * 16 + sub;
    uint4 pv; pv.x = 0; pv.y = 0; pv.z = 0; pv.w = 0;
    if (mode && wr && sub < 13) pv = ((const uint4*)prev)[qi];  // overlaps the shfl chain
#pragma unroll
    for (int j = 0; j < 8; ++j) a[j] += __shfl_xor(a[j], 16);
#pragma unroll
    for (int j = 0; j < 8; ++j) a[j] += __shfl_xor(a[j], 32);
    if (!wr) return;
    if (sub >= 13) {  // pure pad quads (features 104..127): keep exact zero
      uint4 z; z.x = 0; z.y = 0; z.z = 0; z.w = 0;
      oq[qi] = z;
      return;
    }
    if (sub == 12) { a[4] = 0.f; a[5] = 0.f; a[6] = 0.f; a[7] = 0.f; }  // features 100..103 = pad
    float rr[8];
    if (mode) {  // out = 2*prop - prev ; prev pads are zero so pads stay exactly zero
      float2 p;
      p = b2f2(pv.x); rr[0] = 2.f * a[0] - p.x; rr[1] = 2.f * a[1] - p.y;
      p = b2f2(pv.y); rr[2] = 2.f * a[2] - p.x; rr[3] = 2.f * a[3] - p.y;
      p = b2f2(pv.z); rr[4] = 2.f * a[4] - p.x; rr[5] = 2.f * a[5] - p.y;
      p = b2f2(pv.w); rr[6] = 2.f * a[6] - p.x; rr[7] = 2.f * a[7] - p.y;
    } else {
#pragma unroll
      for (int j = 0; j < 8; ++j) rr[j] = a[j];
    }
    uint4 pk;
    pk.x = (uint32)f2b(rr[0]) | ((uint32)f2b(rr[1]) << 16);
    pk.y = (uint32)f2b(rr[2]) | ((uint32)f2b(rr[3]) << 16);
    pk.z = (uint32)f2b(rr[4]) | ((uint32)f2b(rr[5]) << 16);
    pk.w = (uint32)f2b(rr[6]) | ((uint32)f2b(rr[7]) << 16);
    oq[qi] = pk;
  };

  float a[8];
#pragma unroll
  for (int j = 0; j < 8; ++j) a[j] = 0.f;
  int li = 0, r = 0, nr = nrOf(0);
  uint4 va, vb;
  float wa, wb;
  issueLoads(0, 0, va, vb, wa, wb);
  for (;;) {
    int nli = li, nrr = r + 1;
    bool fin = (nrr >= nr);
    if (fin) { nli = li + 1; nrr = 0; }
    bool more = (nli < cnt);
    uint4 va2, vb2;
    float wa2 = 0.f, wb2 = 0.f;
    if (more) issueLoads(nli, nrr, va2, vb2, wa2, wb2);  // issue BEFORE consuming current
    acc8(a, va, wa);
    acc8(a, vb, wb);
    if (fin) {
      finishNode(li, a);  // tail overlaps next node's in-flight gathers
#pragma unroll
      for (int j = 0; j < 8; ++j) a[j] = 0.f;
      if (more) nr = nrOf(nli);
    }
    if (!more) break;
    li = nli; r = nrr;
    va = va2; vb = vb2; wa = wa2; wb = wb2;
  }
}

// ---------------- W repack: fp32 [mat][c][f] -> bf16 MFMA B-fragments ----------------

__global__ __launch_bounds__(64) void wconv(const float* __restrict__ Wr, ushort16* __restrict__ Wf) {
  int b = blockIdx.x;
  int l = threadIdx.x;
  int mat = b / 28, rem = b % 28;
  int kc = rem / 7, ft = rem % 7;
  const float* Wm = Wr + (size_t)mat * H * H;
  int c0 = kc * 32 + (l >> 4) * 8;
  int f = ft * 16 + (l & 15);
  ushort16 vals[8];
#pragma unroll
  for (int j = 0; j < 8; ++j) {
    int c = c0 + j;
    float v = (c < H && f < H) ? Wm[c * H + f] : 0.f;
    vals[j] = f2b(v);
  }
  uint4 pk;
  pk.x = (uint32)vals[0] | ((uint32)vals[1] << 16);
  pk.y = (uint32)vals[2] | ((uint32)vals[3] << 16);
  pk.z = (uint32)vals[4] | ((uint32)vals[5] << 16);
  pk.w = (uint32)vals[6] | ((uint32)vals[7] << 16);
  *(uint4*)(Wf + (size_t)b * 512 + l * 8) = pk;
}

// ---------------- MFMA GEMM: C[N,100] (+)= sum_k Tk @ Wk, up to 5 T operands ----------------
// doStats: fused relu+sum/sumsq epilogue (per-wave shfl reduce -> LDS -> 200 atomics/block).

__global__ __launch_bounds__(256) void gemm_mfma(const ushort16* __restrict__ Ta, const ushort16* __restrict__ Tb,
                                                 const ushort16* __restrict__ Tc, const ushort16* __restrict__ Td,
                                                 const ushort16* __restrict__ Te, int nk,
                                                 const ushort16* __restrict__ Wf, const float* __restrict__ bias,
                                                 float* __restrict__ C, int n, int initMode,
                                                 float* __restrict__ stats, int doStats) {
  __shared__ float sred[4][2][112];
  int t = threadIdx.x;
  int w = t >> 6, l = t & 63;
  int ml = l & 15, quad = l >> 4;
  int n0 = blockIdx.x * 128 + 32 * w;

  f4v acc[2][7];
  if (initMode) {
#pragma unroll
    for (int ft = 0; ft < 7; ++ft) {
      int f = ft * 16 + ml;
      float b = (f < H) ? bias[f] : 0.f;
      f4v v = {b, b, b, b};
      acc[0][ft] = v;
      acc[1][ft] = v;
    }
  } else {
#pragma unroll
    for (int s = 0; s < 2; ++s)
#pragma unroll
      for (int ft = 0; ft < 7; ++ft) {
        int f = ft * 16 + ml;
#pragma unroll
        for (int r = 0; r < 4; ++r) {
          int row = n0 + 16 * s + quad * 4 + r;
          acc[s][ft][r] = (f < H && row < n) ? C[(size_t)row * H + f] : 0.f;
        }
      }
  }

  for (int k = 0; k < nk; ++k) {
    const ushort16* T = (k == 0) ? Ta : (k == 1) ? Tb : (k == 2) ? Tc : (k == 3) ? Td : Te;
#pragma unroll
    for (int kc = 0; kc < 4; ++kc) {
      s8v bfrag[7];
      const ushort16* wb = Wf + ((size_t)(k * 4 + kc) * 7) * 512 + l * 8;
#pragma unroll
      for (int ft = 0; ft < 7; ++ft) bfrag[ft] = *(const s8v*)(wb + ft * 512);
#pragma unroll
      for (int s = 0; s < 2; ++s) {
        const ushort16* ap = T + (size_t)(n0 + 16 * s + ml) * 128 + kc * 32 + quad * 8;
        s8v a = *(const s8v*)ap;
#pragma unroll
        for (int ft = 0; ft < 7; ++ft)
          acc[s][ft] = __builtin_amdgcn_mfma_f32_16x16x32_bf16(a, bfrag[ft], acc[s][ft], 0, 0, 0);
      }
    }
  }

#pragma unroll
  for (int s = 0; s < 2; ++s)
#pragma unroll
    for (int ft = 0; ft < 7; ++ft) {
      int f = ft * 16 + ml;
      if (f < H) {
#pragma unroll
        for (int r = 0; r < 4; ++r) {
          int row = n0 + 16 * s + quad * 4 + r;
          if (row < n) C[(size_t)row * H + f] = acc[s][ft][r];
        }
      }
    }

  if (doStats) {
#pragma unroll
    for (int ft = 0; ft < 7; ++ft) {
      float s1 = 0.f, s2 = 0.f;
#pragma unroll
      for (int s = 0; s < 2; ++s)
#pragma unroll
        for (int r = 0; r < 4; ++r) {
          int row = n0 + 16 * s + quad * 4 + r;
          float v = (row < n) ? fmaxf(acc[s][ft][r], 0.f) : 0.f;
          s1 += v;
          s2 = fmaf(v, v, s2);
        }
      s1 += __shfl_xor(s1, 16); s1 += __shfl_xor(s1, 32);
      s2 += __shfl_xor(s2, 16); s2 += __shfl_xor(s2, 32);
      if (quad == 0) {
        sred[w][0][ft * 16 + ml] = s1;
        sred[w][1][ft * 16 + ml] = s2;
      }
    }
    __syncthreads();
    if (t < 112 && t < H) {
      float s1 = sred[0][0][t] + sred[1][0][t] + sred[2][0][t] + sred[3][0][t];
      float s2 = sred[0][1][t] + sred[1][1][t] + sred[2][1][t] + sred[3][1][t];
      atomicAdd(&stats[t], s1);
      atomicAdd(&stats[128 + t], s2);
    }
  }
}

// ---------------- layer 0 dense part ----------------

__global__ __launch_bounds__(128) void layer0_out(const float* __restrict__ x, const float* __restrict__ t1,
                                                  const float* __restrict__ t2, const float* __restrict__ t3,
                                                  const float* __restrict__ t4, const float* __restrict__ W0,
                                                  const float* __restrict__ b0, float* __restrict__ C, int n) {
  int f = threadIdx.x;
  bool act = f < H;
  float w[10];
  float b = 0.f;
  if (act) {
#pragma unroll
    for (int j = 0; j < 10; ++j) w[j] = W0[j * H + f];
    b = b0[f];
  }
  int n0 = blockIdx.x * 32;
  int n1 = n0 + 32 < n ? n0 + 32 : n;
  for (int i = n0; i < n1; ++i) {
    if (!act) continue;
    float acc = b;
    acc = fmaf(x[2 * i],      w[0], acc);
    acc = fmaf(x[2 * i + 1],  w[1], acc);
    acc = fmaf(t1[2 * i],     w[2], acc);
    acc = fmaf(t1[2 * i + 1], w[3], acc);
    acc = fmaf(t2[2 * i],     w[4], acc);
    acc = fmaf(t2[2 * i + 1], w[5], acc);
    acc = fmaf(t3[2 * i],     w[6], acc);
    acc = fmaf(t3[2 * i + 1], w[7], acc);
    acc = fmaf(t4[2 * i],     w[8], acc);
    acc = fmaf(t4[2 * i + 1], w[9], acc);
    C[(size_t)i * H + f] = acc;
  }
}

// ---------------- batch norm ----------------

__global__ __launch_bounds__(128) void bn_stats(const float* __restrict__ acc, float* __restrict__ stats, int n) {
  int f = threadIdx.x;
  int n0 = blockIdx.x * 512;
  int n1 = n0 + 512 < n ? n0 + 512 : n;
  if (f < H) {
    float s = 0.f, s2 = 0.f;
    for (int i = n0; i < n1; ++i) {
      float v = fmaxf(acc[(size_t)i * H + f], 0.f);
      s += v;
      s2 = fmaf(v, v, s2);
    }
    atomicAdd(&stats[f], s);
    atomicAdd(&stats[128 + f], s2);
  }
}

__global__ __launch_bounds__(128) void bn_params(float* __restrict__ stats, const float* __restrict__ gamma,
                                                 const float* __restrict__ beta, int n) {
  int f = threadIdx.x;
  if (f >= H) return;
  float inv_n = 1.f / (float)n;
  float m = stats[f] * inv_n;
  float v = stats[128 + f] * inv_n - m * m;
  float is = rsqrtf(v + 1e-5f);
  float g = gamma[f] * is;
  stats[256 + f] = g;                // scale
  stats[384 + f] = beta[f] - m * g;  // shift
}

// fp32 out (final layer, in-place over C)
__global__ __launch_bounds__(256) void bn_final(const float* __restrict__ acc, const float* __restrict__ mi,
                                                float* __restrict__ out, int total) {
  int idx = blockIdx.x * 256 + threadIdx.x;
  if (idx >= total) return;
  int f = idx % H;
  float v = fmaxf(acc[idx], 0.f);
  out[idx] = fmaf(v, mi[f], mi[128 + f]);
}

// bf16 out, vectorized: thread = 8 features (one uint4 quad), subs 0..12 per row.
// Pads within sub 12 (f 100..103) written zero; subs 13..15 untouched (already zero).
__global__ __launch_bounds__(256) void bn_final_bf16v(const float* __restrict__ acc, const float* __restrict__ mi,
                                                      uint4* __restrict__ out, int n) {
  int idx = blockIdx.x * 256 + threadIdx.x;
  if (idx >= n * 13) return;
  int row = idx / 13, s = idx - row * 13;
  int f0 = s * 8;
  const float* cr = acc + (size_t)row * H;
  float v[8];
#pragma unroll
  for (int j = 0; j < 8; ++j) {
    int f = f0 + j;
    int fc = (f < H) ? f : 0;  // clamp address; value masked below
    float c = fmaxf(cr[fc], 0.f);
    v[j] = (f < H) ? fmaf(c, mi[f], mi[128 + f]) : 0.f;
  }
  uint4 pk;
  pk.x = (uint32)f2b(v[0]) | ((uint32)f2b(v[1]) << 16);
  pk.y = (uint32)f2b(v[2]) | ((uint32)f2b(v[3]) << 16);
  pk.z = (uint32)f2b(v[4]) | ((uint32)f2b(v[5]) << 16);
  pk.w = (uint32)f2b(v[6]) | ((uint32)f2b(v[7]) << 16);
  out[(size_t)row * 16 + s] = pk;
}

// ---------------- launch ----------------

extern "C" void kernel_launch(void* const* d_in, const int* in_sizes, int n_in,
                              void* d_out, int out_size, void* d_ws, size_t ws_size,
                              hipStream_t stream) {
  const float* x     = (const float*)d_in[0];
  const int*   ei    = (const int*)d_in[1];
  const float* W0    = (const float*)d_in[2];
  const float* b0    = (const float*)d_in[3];
  const float* Wr    = (const float*)d_in[4];
  const float* br    = (const float*)d_in[5];
  const float* gamma = (const float*)d_in[6];
  const float* beta  = (const float*)d_in[7];
  float* C = (float*)d_out;

  const int N = in_sizes[0] / FIN;
  const int E = in_sizes[1] / 2;
  const int* src = ei;
  const int* dst = ei + E;

  char* ws = (char*)d_ws;
  size_t off = 0;
  auto alloc = [&](size_t bytes) -> void* {
    void* p = ws + off;
    off = (off + bytes + 255) & ~(size_t)255;
    return p;
  };

  size_t TB = (size_t)N * 128 * sizeof(ushort16);  // bf16, stride-128 rows
  ushort16* B0     = (ushort16*)alloc(TB);
  ushort16* B1     = (ushort16*)alloc(TB);
  ushort16* B2     = (ushort16*)alloc(TB);
  ushort16* Wf     = (ushort16*)alloc((size_t)20 * 14336 * sizeof(ushort16));
  float* t1       = (float*)alloc((size_t)N * 2 * 4);
  float* t2       = (float*)alloc((size_t)N * 2 * 4);
  float* t3       = (float*)alloc((size_t)N * 2 * 4);
  float* t4       = (float*)alloc((size_t)N * 2 * 4);
  float* deg      = (float*)alloc((size_t)N * 4);
  int*   indeg    = (int*)alloc((size_t)N * 4);
  float* dinv     = (float*)alloc((size_t)N * 4);
  int*   incl     = (int*)alloc((size_t)N * 4);
  int*   bsum     = (int*)alloc(8192 * 4);
  int*   bscan    = (int*)alloc(8192 * 4);
  int*   offsets  = (int*)alloc((size_t)(N + 1) * 4);
  int*   cursor   = (int*)alloc((size_t)N * 4);
  int2*  csr      = (int2*)alloc((size_t)E * 8);
  float* stats    = (float*)alloc(512 * 4);

  // Two extra T buffers (single-gemm-per-layer path) if workspace allows.
  ushort16* B3 = B0;
  ushort16* B4 = B1;
  bool five = (off + 2 * TB + 512 <= ws_size);
  if (five) {
    B3 = (ushort16*)alloc(TB);
    B4 = (ushort16*)alloc(TB);
  }

  int gE = (E + 255) / 256;
  int gN = (N + 255) / 256;

  hipMemsetAsync(deg, 0, (size_t)N * 4, stream);
  hipMemsetAsync(indeg, 0, (size_t)N * 4, stream);

  deg_kernel<<<gE, 256, 0, stream>>>(src, dst, deg, indeg, E);
  dinv_kernel<<<gN, 256, 0, stream>>>(deg, dinv, N);
  scan_block<<<gN, 256, 0, stream>>>(indeg, incl, bsum, N);
  scan_sums<<<1, 256, 0, stream>>>(bsum, bscan, gN);
  finalize_offsets<<<gN, 256, 0, stream>>>(incl, indeg, bscan, offsets, cursor, N, E);
  build_csr<<<gE, 256, 0, stream>>>(src, dst, dinv, cursor, csr, E);
  wconv<<<20 * 28, 64, 0, stream>>>(Wr, Wf);
  pad_zero<<<(N * 4 + 255) / 256, 256, 0, stream>>>((uint4*)B0, N);  // other B pads written by prop_hb3

  // ---- layer 0 (F_IN = 2) ----
  prop2<<<gN, 256, 0, stream>>>(x,  x,  t1, offsets, csr, N, 0);
  prop2<<<gN, 256, 0, stream>>>(t1, x,  t2, offsets, csr, N, 1);
  prop2<<<gN, 256, 0, stream>>>(t2, t1, t3, offsets, csr, N, 1);
  prop2<<<gN, 256, 0, stream>>>(t3, t2, t4, offsets, csr, N, 1);
  layer0_out<<<(N + 31) / 32, 128, 0, stream>>>(x, t1, t2, t3, t4, W0, b0, C, N);
  hipMemsetAsync(stats, 0, 1024, stream);
  bn_stats<<<(N + 511) / 512, 128, 0, stream>>>(C, stats, N);
  bn_params<<<1, 128, 0, stream>>>(stats, gamma, beta, N);
  bn_final_bf16v<<<(N * 13 + 255) / 256, 256, 0, stream>>>(C, stats + 256, (uint4*)B0, N);

  // ---- layers 1..4 (H = 100, bf16 T buffers, MFMA GEMMs) ----
  int gG = (N + 127) / 128;
  int gP = (N + NPB - 1) / NPB;
  for (int layer = 1; layer < 5; ++layer) {
    const ushort16* WfL = Wf + (size_t)(layer - 1) * 5 * 14336;
    const float* bl = br + (size_t)(layer - 1) * H;
    if (five) {
      // T1..T4 into B1..B4, then one gemm over all 5 Chebyshev terms (stats fused)
      prop_hb3<<<gP, 256, 0, stream>>>((const uint32*)B0, (const uint32*)B0, (uint32*)B1, offsets, csr, N, 0);
      prop_hb3<<<gP, 256, 0, stream>>>((const uint32*)B1, (const uint32*)B0, (uint32*)B2, offsets, csr, N, 1);
      prop_hb3<<<gP, 256, 0, stream>>>((const uint32*)B2, (const uint32*)B1, (uint32*)B3, offsets, csr, N, 1);
      prop_hb3<<<gP, 256, 0, stream>>>((const uint32*)B3, (const uint32*)B2, (uint32*)B4, offsets, csr, N, 1);
      hipMemsetAsync(stats, 0, 1024, stream);
      gemm_mfma<<<gG, 256, 0, stream>>>(B0, B1, B2, B3, B4, 5, WfL, bl, C, N, 1, stats, 1);
    } else {
      prop_hb3<<<gP, 256, 0, stream>>>((const uint32*)B0, (const uint32*)B0, (uint32*)B1, offsets, csr, N, 0);
      prop_hb3<<<gP, 256, 0, stream>>>((const uint32*)B1, (const uint32*)B0, (uint32*)B2, offsets, csr, N, 1);
      gemm_mfma<<<gG, 256, 0, stream>>>(B0, B1, B2, B0, B1, 3, WfL, bl, C, N, 1, stats, 0);
      prop_hb3<<<gP, 256, 0, stream>>>((const uint32*)B2, (const uint32*)B1, (uint32*)B0, offsets, csr, N, 1);
      prop_hb3<<<gP, 256, 0, stream>>>((const uint32*)B0, (const uint32*)B2, (uint32*)B1, offsets, csr, N, 1);
      gemm_mfma<<<gG, 256, 0, stream>>>(B0, B1, B0, B0, B1, 2, WfL + (size_t)3 * 14336, bl, C, N, 0, stats, 0);
      hipMemsetAsync(stats, 0, 1024, stream);
      bn_stats<<<(N + 511) / 512, 128, 0, stream>>>(C, stats, N);
    }
    bn_params<<<1, 128, 0, stream>>>(stats, gamma + (size_t)layer * H, beta + (size_t)layer * H, N);
    if (layer < 4)
      bn_final_bf16v<<<(N * 13 + 255) / 256, 256, 0, stream>>>(C, stats + 256, (uint4*)B0, N);
    else
      bn_final<<<(N * H + 255) / 256, 256, 0, stream>>>(C, stats + 256, C, N * H);
  }
}